// Round 3
// baseline (1035.425 us; speedup 1.0000x reference)
//
#include <hip/hip_runtime.h>
#include <stdint.h>

// Problem shape (fixed by the reference): M = B*S = 8192, K = DIN = 4096, N = DOUT = 4096
#define MDIM 8192
#define KDIM 4096
#define NDIM 4096
#define BK   64
#define NKT  (KDIM / BK)   // 64 K-tiles

typedef float f32x4 __attribute__((ext_vector_type(4)));
typedef _Float16 h16x8 __attribute__((ext_vector_type(8)));
typedef float fl4 __attribute__((ext_vector_type(4)));
typedef int i32x4 __attribute__((ext_vector_type(4)));

// ---------------- fully-fused W8A8 GEMM: quant-in-staging, zero workspace ----------------
// R6: one dispatch. A = rint(x/is) (fp16, integer-exact to 2048), B = (fp16)w, staged
// via reg-staging (global fp32/int32 -> VGPR -> cvt -> ds_write_b128) instead of
// global_load_lds, so quantization fuses into the GEMM and BOTH the quant dispatch and
// the 96 MiB workspace disappear (tests H1 quant-GPU-time vs H3 ws-re-poison residual).
//
// 256x256 tile, BK=64, 8 waves (2Mx4N), 8-phase schedule, T2 XOR swizzle, T5 setprio.
// T14 staging: each phase ISSUES one half-tile's loads (4x dwordx4/thread) and WRITES the
// group issued 2 phases earlier (compiler inserts the counted vmcnt before the cvt use;
// sched_barrier(0) at phase edges pins placement). Never a vmcnt(0) drain in the loop.
//
// Region last-read (phase) -> written (phase, tile):
//   buf0.A.h0: read P0 -> write P4 (tA)     buf1.A.h0: read P4 -> write nextP0 (tB)
//   buf0.A.h1: read P2 -> write P5 (tA)     buf1.A.h1: read P6 -> write nextP1 (tB)
//   buf0.B.h0: read P1 -> write P2 (tA)     buf1.B.h0: read P5 -> write P6 (tB)
//   buf0.B.h1: read P1 -> write P3 (tA)     buf1.B.h1: read P5 -> write P7 (tB)
// Issue->write is uniformly +2 phases: P0->P2, P1->P3, ..., P6->nextP0, P7->nextP1,
// carried by 4 statically-named reg groups (vA0,vA1 fp32; vB0,vB1 int32).
// Same-phase write/read regions are disjoint in every phase (checked per phase).

#define PH_MID() do { \
    __builtin_amdgcn_s_barrier(); \
    asm volatile("s_waitcnt lgkmcnt(0)" ::: "memory"); \
    __builtin_amdgcn_sched_barrier(0); \
    __builtin_amdgcn_s_setprio(1); \
  } while (0)

#define PH_END() do { \
    __builtin_amdgcn_s_setprio(0); \
    __builtin_amdgcn_s_barrier(); \
    __builtin_amdgcn_sched_barrier(0); \
  } while (0)

__global__ void __launch_bounds__(512, 2) gemm_fused_kernel(
    const float* __restrict__ x,     // [MDIM][KDIM] fp32
    const int* __restrict__ w,       // [NDIM][KDIM] int32 (int8-valued)
    const int* __restrict__ bias,    // [NDIM]
    const float* __restrict__ wscale,// [NDIM]
    const float* __restrict__ p_is,
    const float* __restrict__ p_os,
    int* __restrict__ out) {         // [MDIM][NDIM] int32
    // A bufs: lds[b*16384 + row*64 + ch*8]; B bufs: +32768. 65536 shorts = 128 KiB.
    __shared__ __align__(16) short lds[65536];

    const int tid  = threadIdx.x;
    const int lane = tid & 63;
    const int wave = tid >> 6;
    const int quad = lane >> 4;
    const int r16  = lane & 15;
    const int sw   = r16 & 7;

    const float inv_is = 1.0f / p_is[0];

    // T1: bijective XCD swizzle over the 32x16 grid (flat = by*16+bx, 512 blocks)
    const int flat  = blockIdx.y * gridDim.x + blockIdx.x;
    const int wgid  = (flat & 7) * 64 + (flat >> 3);
    const int m_blk = wgid >> 4;       // 0..31
    const int n_blk = wgid & 15;       // 0..15
    const int m0 = m_blk * 256;
    const int n0 = n_blk * 256;

    const int wmi = wave >> 2;         // 0..1  M wave-row (128 rows each)
    const int wni = wave & 3;          // 0..3  N wave-col (64 cols each)

    // ---- staging geometry: thread tid owns rows {srow, srow+64} of a half-tile,
    //      k-chunk skc (XOR-swizzled source so LDS chunk (row,c) holds global c^(row&7)).
    const int srow = tid >> 3;                       // 0..63
    const int skc  = (tid & 7) ^ (srow & 7);
    const float* xg = x + (int64_t)(m0 + srow) * KDIM + skc * 8;
    const int*   wg = w + (int64_t)(n0 + srow) * KDIM + skc * 8;

    // LDS dest (short idx): region base + tid*8 (rows srow) / +4096 (rows srow+64)
#define DS_WRITE2(baseShorts, o1, o2) do { \
    *(h16x8*)(&lds[(baseShorts) + tid * 8])        = (o1); \
    *(h16x8*)(&lds[(baseShorts) + 4096 + tid * 8]) = (o2); \
  } while (0)

    // issue one half-tile's global loads into a named reg group (4x dwordx4)
#define LOAD_A(v, ha, T) do { \
    const float* _p = xg + (int64_t)((ha) * 128) * KDIM + (T) * BK; \
    v[0] = *(const fl4*)_p;              v[1] = *(const fl4*)(_p + 4); \
    v[2] = *(const fl4*)(_p + 64*KDIM);  v[3] = *(const fl4*)(_p + 64*KDIM + 4); \
  } while (0)
#define LOAD_B(v, ha, T) do { \
    const int* _p = wg + (int64_t)((ha) * 128) * KDIM + (T) * BK; \
    v[0] = *(const i32x4*)_p;             v[1] = *(const i32x4*)(_p + 4); \
    v[2] = *(const i32x4*)(_p + 64*KDIM); v[3] = *(const i32x4*)(_p + 64*KDIM + 4); \
  } while (0)

#define CVT_A(o, p, q) do { \
    o[0] = (_Float16)rintf(p[0] * inv_is); o[1] = (_Float16)rintf(p[1] * inv_is); \
    o[2] = (_Float16)rintf(p[2] * inv_is); o[3] = (_Float16)rintf(p[3] * inv_is); \
    o[4] = (_Float16)rintf(q[0] * inv_is); o[5] = (_Float16)rintf(q[1] * inv_is); \
    o[6] = (_Float16)rintf(q[2] * inv_is); o[7] = (_Float16)rintf(q[3] * inv_is); \
  } while (0)
#define CVT_B(o, p, q) do { \
    o[0] = (_Float16)(float)p[0]; o[1] = (_Float16)(float)p[1]; \
    o[2] = (_Float16)(float)p[2]; o[3] = (_Float16)(float)p[3]; \
    o[4] = (_Float16)(float)q[0]; o[5] = (_Float16)(float)q[1]; \
    o[6] = (_Float16)(float)q[2]; o[7] = (_Float16)(float)q[3]; \
  } while (0)

#define WRITE_A(baseShorts, v) do { \
    h16x8 _o1, _o2; CVT_A(_o1, v[0], v[1]); CVT_A(_o2, v[2], v[3]); \
    DS_WRITE2(baseShorts, _o1, _o2); \
  } while (0)
#define WRITE_B(baseShorts, v) do { \
    h16x8 _o1, _o2; CVT_B(_o1, v[0], v[1]); CVT_B(_o2, v[2], v[3]); \
    DS_WRITE2(baseShorts, _o1, _o2); \
  } while (0)

    // region bases (short idx): A: b*16384 + ha*8192; B: 32768 + b*16384 + ha*8192
#define A_B0H0 0
#define A_B0H1 8192
#define A_B1H0 16384
#define A_B1H1 24576
#define B_B0H0 32768
#define B_B0H1 40960
#define B_B1H0 49152
#define B_B1H1 57344

    // ---- read side: row = <mult of 8> + r16, so row&7 == sw; chunk = (ks*4|quad)^sw
    const int aRowOff = (wmi * 128 + r16) * 64;          // + (mh*64 + mi*16)*64
    const int bRowOff = 32768 + (wni * 64 + r16) * 64;   // + (nh*32 + nj*16)*64
    const int cOff0   = (quad ^ sw) * 8;
    const int cOff1   = cOff0 ^ 32;                      // ks=1 flips chunk bit 2

#define LDA(b, mh, mi, ks) \
    (*(const h16x8*)&lds[(b)*16384 + aRowOff + ((mh)*64 + (mi)*16)*64 + ((ks) ? cOff1 : cOff0)])
#define LDB(b, nh, nj, ks) \
    (*(const h16x8*)&lds[(b)*16384 + bRowOff + ((nh)*32 + (nj)*16)*64 + ((ks) ? cOff1 : cOff0)])

#define READ_A(b, mh) do { \
    _Pragma("unroll") for (int mi = 0; mi < 4; ++mi) { \
        aR[mi][0] = LDA(b, mh, mi, 0); aR[mi][1] = LDA(b, mh, mi, 1); } \
  } while (0)
#define READ_B(b, nh, dst) do { \
    _Pragma("unroll") for (int nj = 0; nj < 2; ++nj) { \
        dst[nj][0] = LDB(b, nh, nj, 0); dst[nj][1] = LDB(b, nh, nj, 1); } \
  } while (0)
#define MFMA_Q(mh, nh, bsrc) do { \
    _Pragma("unroll") for (int mi = 0; mi < 4; ++mi) \
    _Pragma("unroll") for (int nj = 0; nj < 2; ++nj) \
    _Pragma("unroll") for (int ks = 0; ks < 2; ++ks) \
        acc[(mh)*4 + mi][(nh)*2 + nj] = __builtin_amdgcn_mfma_f32_16x16x32_f16( \
            aR[mi][ks], bsrc[nj][ks], acc[(mh)*4 + mi][(nh)*2 + nj], 0, 0, 0); \
  } while (0)

    f32x4 acc[8][4];
#pragma unroll
    for (int i = 0; i < 8; ++i)
#pragma unroll
        for (int j = 0; j < 4; ++j) acc[i][j] = (f32x4)0.0f;

    h16x8 aR[4][2], bLo[2][2], bHi[2][2];
    fl4   vA0[4], vA1[4];   // fp32 A staging groups (issue->write gap = 2 phases)
    i32x4 vB0[4], vB1[4];   // int32 B staging groups

    // ---- prologue: stage t0 fully + t1.B; leave t1.A in regs for in-loop P0/P1 ----
    LOAD_A(vA0, 0, 0); LOAD_A(vA1, 1, 0);
    LOAD_B(vB0, 0, 0); LOAD_B(vB1, 1, 0);
    WRITE_A(A_B0H0, vA0); WRITE_A(A_B0H1, vA1);
    WRITE_B(B_B0H0, vB0); WRITE_B(B_B0H1, vB1);
    LOAD_B(vB0, 0, 1); LOAD_B(vB1, 1, 1);
    WRITE_B(B_B1H0, vB0); WRITE_B(B_B1H1, vB1);
    LOAD_A(vA0, 0, 1); LOAD_A(vA1, 1, 1);          // t1.A -> written at P0/P1
    asm volatile("s_waitcnt lgkmcnt(0)" ::: "memory");
    __builtin_amdgcn_s_barrier();
    __builtin_amdgcn_sched_barrier(0);

    for (int it = 0; it < NKT / 2; ++it) {
        const int tA = (2 * it + 2) & (NKT - 1);   // wraps harmlessly on last iter
        const int tB = (2 * it + 3) & (NKT - 1);

        // P0: compute buf0 q(mh0,nlo); write t1.A.h0; issue tA.B.h0
        READ_A(0, 0); READ_B(0, 0, bLo);
        WRITE_A(A_B1H0, vA0);
        LOAD_B(vB0, 0, tA);
        PH_MID(); MFMA_Q(0, 0, bLo); PH_END();
        // P1: q(mh0,nhi); write t1.A.h1; issue tA.B.h1
        READ_B(0, 1, bHi);
        WRITE_A(A_B1H1, vA1);
        LOAD_B(vB1, 1, tA);
        PH_MID(); MFMA_Q(0, 1, bHi); PH_END();
        // P2: q(mh1,nhi); write tA.B.h0 (buf0.B free since P1); issue tA.A.h0
        READ_A(0, 1);
        WRITE_B(B_B0H0, vB0);
        LOAD_A(vA0, 0, tA);
        PH_MID(); MFMA_Q(1, 1, bHi); PH_END();
        // P3: q(mh1,nlo); write tA.B.h1; issue tA.A.h1
        WRITE_B(B_B0H1, vB1);
        LOAD_A(vA1, 1, tA);
        PH_MID(); MFMA_Q(1, 0, bLo); PH_END();
        // P4: compute buf1 q(mh0,nlo); write tA.A.h0 (buf0.A free since P2); issue tB.B.h0
        READ_A(1, 0); READ_B(1, 0, bLo);
        WRITE_A(A_B0H0, vA0);
        LOAD_B(vB0, 0, tB);
        PH_MID(); MFMA_Q(0, 0, bLo); PH_END();
        // P5: q(mh0,nhi); write tA.A.h1; issue tB.B.h1
        READ_B(1, 1, bHi);
        WRITE_A(A_B0H1, vA1);
        LOAD_B(vB1, 1, tB);
        PH_MID(); MFMA_Q(0, 1, bHi); PH_END();
        // P6: q(mh1,nhi); write tB.B.h0 (buf1.B free since P5); issue tB.A.h0
        READ_A(1, 1);
        WRITE_B(B_B1H0, vB0);
        LOAD_A(vA0, 0, tB);
        PH_MID(); MFMA_Q(1, 1, bHi); PH_END();
        // P7: q(mh1,nlo); write tB.B.h1; issue tB.A.h1 (written next-iter P0/P1)
        WRITE_B(B_B1H1, vB1);
        LOAD_A(vA1, 1, tB);
        PH_MID(); MFMA_Q(1, 0, bLo); PH_END();
    }

    // ---- epilogue: out = round((is*ws[n]*acc + bias[n]) / os) ----
    const float is = p_is[0];
    const float inv_os = 1.0f / p_os[0];
    const int colBase = n0 + wni * 64;

    float alpha[4], beta[4];
#pragma unroll
    for (int nj = 0; nj < 4; ++nj) {
        const int col = colBase + nj * 16 + r16;
        alpha[nj] = is * wscale[col] * inv_os;
        beta[nj]  = (float)bias[col] * inv_os;
    }

    // C/D layout (verified m89/m91, dtype-independent): col = lane&15, row = quad*4 + reg
#pragma unroll
    for (int mi = 0; mi < 8; ++mi) {
        const int row0 = m0 + wmi * 128 + mi * 16 + quad * 4;
#pragma unroll
        for (int nj = 0; nj < 4; ++nj) {
            const int col = colBase + nj * 16 + r16;
#pragma unroll
            for (int reg = 0; reg < 4; ++reg) {
                const float v = acc[mi][nj][reg] * alpha[nj] + beta[nj];
                __builtin_nontemporal_store(__float2int_rn(v),
                                            out + (int64_t)(row0 + reg) * NDIM + col);
            }
        }
    }
}

extern "C" void kernel_launch(void* const* d_in, const int* in_sizes, int n_in,
                              void* d_out, int out_size, void* d_ws, size_t ws_size,
                              hipStream_t stream) {
    (void)in_sizes; (void)n_in; (void)out_size; (void)d_ws; (void)ws_size;
    const float* x      = (const float*)d_in[0];
    const int*   weight = (const int*)d_in[1];
    const int*   bias   = (const int*)d_in[2];
    const float* wscale = (const float*)d_in[3];
    const float* p_is   = (const float*)d_in[4];
    const float* p_os   = (const float*)d_in[5];

    dim3 grid(NDIM / 256, MDIM / 256);   // 16 x 32 = 512 blocks
    gemm_fused_kernel<<<grid, 512, 0, stream>>>(x, weight, bias, wscale, p_is, p_os,
                                                (int*)d_out);
}

// Round 5
// 629.098 us; speedup vs baseline: 1.6459x; 1.6459x over previous
//
#include <hip/hip_runtime.h>
#include <stdint.h>

// Problem shape (fixed by the reference): M = B*S = 8192, K = DIN = 4096, N = DOUT = 4096
#define MDIM 8192
#define KDIM 4096
#define NDIM 4096
#define BK   64
#define NKT  (KDIM / BK)   // 64 K-tiles

typedef float f32x4 __attribute__((ext_vector_type(4)));
typedef _Float16 h16x8 __attribute__((ext_vector_type(8)));
typedef __fp16 fp16x2 __attribute__((ext_vector_type(2)));   // native cvt_pkrtz result type
typedef float fl4 __attribute__((ext_vector_type(4)));
typedef int i32x4 __attribute__((ext_vector_type(4)));

// async global->LDS, 16B per lane; LDS dest is wave-uniform base + lane*16 (HW semantics)
__device__ __forceinline__ void gload_lds16(const void* g, void* l) {
    __builtin_amdgcn_global_load_lds(
        (__attribute__((address_space(1))) void*)(uintptr_t)g,
        (__attribute__((address_space(3))) void*)(uintptr_t)l,
        16, 0, 0);
}

// ---------------- w-prepass: int32 [N,K] -> fp16 bits [N,K] (|w|<=127: exact) ----------------
// NT loads (w read once); normal stores (gemm re-reads wq; 32 MiB stays L3-resident).
// v_cvt_pkrtz is exact for integer values (RTZ==RNE when representable).
__global__ void __launch_bounds__(256) quant_w_kernel(const int* __restrict__ w,
                                                      short* __restrict__ wq) {
    const int64_t stride = (int64_t)2048 * 256 * 8;
    for (int64_t i = ((int64_t)blockIdx.x * 256 + threadIdx.x) * 8;
         i < (int64_t)NDIM * KDIM; i += stride) {
        i32x4 a = __builtin_nontemporal_load((const i32x4*)(w + i));
        i32x4 b = __builtin_nontemporal_load((const i32x4*)(w + i + 4));
        fp16x2 p0 = __builtin_amdgcn_cvt_pkrtz((float)a[0], (float)a[1]);
        fp16x2 p1 = __builtin_amdgcn_cvt_pkrtz((float)a[2], (float)a[3]);
        fp16x2 p2 = __builtin_amdgcn_cvt_pkrtz((float)b[0], (float)b[1]);
        fp16x2 p3 = __builtin_amdgcn_cvt_pkrtz((float)b[2], (float)b[3]);
        h16x8 o;
        o[0] = (_Float16)p0[0]; o[1] = (_Float16)p0[1];
        o[2] = (_Float16)p1[0]; o[3] = (_Float16)p1[1];
        o[4] = (_Float16)p2[0]; o[5] = (_Float16)p2[1];
        o[6] = (_Float16)p3[0]; o[7] = (_Float16)p3[1];
        *(h16x8*)(wq + i) = o;
    }
}

// ---------------- GEMM: x-quant fused into A staging; B via global_load_lds ----------------
// R8 (= R7 + type fix): A = rint(x/is) fp16 computed in staging regs (fp32 global -> VGPR
// -> cvt_pkrtz -> ds_write_b128); B staged with global_load_lds from pre-quantized wq.
// x-quant pass and its 64 MiB xq round-trip disappear. __launch_bounds__(512,1): LDS
// (128 KiB) already forces 1 block/CU, so cap VGPR at 256 not 128 (R3's spill own-goal).
//
// 256x256 tile, BK=64, 8 waves (2Mx4N), 8-phase, T2 XOR swizzle, T5 setprio, T1 XCD swizzle.
//
// Region table (read phase -> staged phase), all barrier-separated:
//   buf0.A: read P0/P2 -> ds_write P4/P5 (regs loaded P2/P3)   buf1.A: read P4/P6 -> next P0/P1 (P6/P7)
//   buf0.B: read P0-P3 -> gload P2/P3 (tA)                     buf1.B: read P4-P7 -> gload P6/P7 (tB)
// vmcnt: NONE explicit in the loop. Compiler auto-inserts a counted vmcnt before each
// CVT use of vA0/vA1 (P4/P5/P0/P1); those loads were issued AFTER the same phase's
// B gload_lds ops, so the auto-wait drains the older B ops too -- every B region is
// landed >=3 phases before its first read. A ds_writes drain at own-phase lgkmcnt(0).

#define PH_MID() do { \
    __builtin_amdgcn_s_barrier(); \
    asm volatile("s_waitcnt lgkmcnt(0)" ::: "memory"); \
    __builtin_amdgcn_sched_barrier(0); \
    __builtin_amdgcn_s_setprio(1); \
  } while (0)

#define PH_END() do { \
    __builtin_amdgcn_s_setprio(0); \
    __builtin_amdgcn_s_barrier(); \
    __builtin_amdgcn_sched_barrier(0); \
  } while (0)

__global__ void __launch_bounds__(512, 1) gemm_fused_kernel(
    const float* __restrict__ x,     // [MDIM][KDIM] fp32
    const short* __restrict__ Bw,    // [NDIM][KDIM] fp16 bits (wq)
    const int* __restrict__ bias,    // [NDIM]
    const float* __restrict__ wscale,// [NDIM]
    const float* __restrict__ p_is,
    const float* __restrict__ p_os,
    int* __restrict__ out) {         // [MDIM][NDIM] int32
    // A bufs: lds[b*16384 + row*64 + ch*8]; B bufs: +32768. 65536 shorts = 128 KiB.
    __shared__ __align__(16) short lds[65536];

    const int tid  = threadIdx.x;
    const int lane = tid & 63;
    const int wave = tid >> 6;
    const int quad = lane >> 4;
    const int r16  = lane & 15;
    const int sw   = r16 & 7;

    const float inv_is = 1.0f / p_is[0];

    // T1: bijective XCD swizzle over the 32x16 grid (flat = by*16+bx, 512 blocks)
    const int flat  = blockIdx.y * gridDim.x + blockIdx.x;
    const int wgid  = (flat & 7) * 64 + (flat >> 3);
    const int m_blk = wgid >> 4;       // 0..31
    const int n_blk = wgid & 15;       // 0..15
    const int m0 = m_blk * 256;
    const int n0 = n_blk * 256;

    const int wmi = wave >> 2;         // 0..1  M wave-row (128 rows each)
    const int wni = wave & 3;          // 0..3  N wave-col (64 cols each)

    // ---- staging geometry: thread tid owns rows {srow, srow+64}, k-chunk skc
    //      (XOR-swizzled source: LDS chunk (row,c) holds global chunk c^(row&7))
    const int srow = tid >> 3;                       // 0..63
    const int skc  = (tid & 7) ^ (srow & 7);
    const float* xg = x  + (int64_t)(m0 + srow) * KDIM + skc * 8;
    const short* gB = Bw + (int64_t)(n0 + srow) * KDIM + skc * 8;

    // B: async global->LDS, linear dest (base + tid*16B inside half-region)
#define STAGE_B(b, ha, T) do { \
    const short* _g = gB + (int64_t)((ha) * 128) * KDIM + (T) * BK; \
    gload_lds16(_g,           &lds[32768 + (b)*16384 + (ha)*8192 + wave*512]); \
    gload_lds16(_g + 64*KDIM, &lds[32768 + (b)*16384 + (ha)*8192 + 4096 + wave*512]); \
  } while (0)

    // A: issue one half-tile's fp32 loads into a named reg group (4x dwordx4/thread)
#define LOAD_A(v, ha, T) do { \
    const float* _p = xg + (int64_t)((ha) * 128) * KDIM + (T) * BK; \
    v[0] = *(const fl4*)_p;              v[1] = *(const fl4*)(_p + 4); \
    v[2] = *(const fl4*)(_p + 64*KDIM);  v[3] = *(const fl4*)(_p + 64*KDIM + 4); \
  } while (0)

    // quantize-pack 8 fp32 -> h16x8 (rint to int grid; pkrtz exact for integers <2048)
#define QPK(a, b) __builtin_amdgcn_cvt_pkrtz(rintf((a) * inv_is), rintf((b) * inv_is))
#define WRITE_A(baseShorts, v) do { \
    fp16x2 p0 = QPK(v[0][0], v[0][1]), p1 = QPK(v[0][2], v[0][3]); \
    fp16x2 p2 = QPK(v[1][0], v[1][1]), p3 = QPK(v[1][2], v[1][3]); \
    fp16x2 q0 = QPK(v[2][0], v[2][1]), q1 = QPK(v[2][2], v[2][3]); \
    fp16x2 q2 = QPK(v[3][0], v[3][1]), q3 = QPK(v[3][2], v[3][3]); \
    h16x8 o1, o2; \
    o1[0]=(_Float16)p0[0]; o1[1]=(_Float16)p0[1]; o1[2]=(_Float16)p1[0]; o1[3]=(_Float16)p1[1]; \
    o1[4]=(_Float16)p2[0]; o1[5]=(_Float16)p2[1]; o1[6]=(_Float16)p3[0]; o1[7]=(_Float16)p3[1]; \
    o2[0]=(_Float16)q0[0]; o2[1]=(_Float16)q0[1]; o2[2]=(_Float16)q1[0]; o2[3]=(_Float16)q1[1]; \
    o2[4]=(_Float16)q2[0]; o2[5]=(_Float16)q2[1]; o2[6]=(_Float16)q3[0]; o2[7]=(_Float16)q3[1]; \
    *(h16x8*)(&lds[(baseShorts) + tid * 8])        = o1; \
    *(h16x8*)(&lds[(baseShorts) + 4096 + tid * 8]) = o2; \
  } while (0)

    // A region bases (short idx)
#define A_B0H0 0
#define A_B0H1 8192
#define A_B1H0 16384
#define A_B1H1 24576

    // ---- read side: row = <mult of 8> + r16, so row&7 == sw; chunk = (ks*4|quad)^sw
    const int aRowOff = (wmi * 128 + r16) * 64;          // + (mh*64 + mi*16)*64
    const int bRowOff = 32768 + (wni * 64 + r16) * 64;   // + (nh*32 + nj*16)*64
    const int cOff0   = (quad ^ sw) * 8;
    const int cOff1   = cOff0 ^ 32;                      // ks=1 flips chunk bit 2

#define LDA(b, mh, mi, ks) \
    (*(const h16x8*)&lds[(b)*16384 + aRowOff + ((mh)*64 + (mi)*16)*64 + ((ks) ? cOff1 : cOff0)])
#define LDB(b, nh, nj, ks) \
    (*(const h16x8*)&lds[(b)*16384 + bRowOff + ((nh)*32 + (nj)*16)*64 + ((ks) ? cOff1 : cOff0)])

#define READ_A(b, mh) do { \
    _Pragma("unroll") for (int mi = 0; mi < 4; ++mi) { \
        aR[mi][0] = LDA(b, mh, mi, 0); aR[mi][1] = LDA(b, mh, mi, 1); } \
  } while (0)
#define READ_B(b, nh, dst) do { \
    _Pragma("unroll") for (int nj = 0; nj < 2; ++nj) { \
        dst[nj][0] = LDB(b, nh, nj, 0); dst[nj][1] = LDB(b, nh, nj, 1); } \
  } while (0)
#define MFMA_Q(mh, nh, bsrc) do { \
    _Pragma("unroll") for (int mi = 0; mi < 4; ++mi) \
    _Pragma("unroll") for (int nj = 0; nj < 2; ++nj) \
    _Pragma("unroll") for (int ks = 0; ks < 2; ++ks) \
        acc[(mh)*4 + mi][(nh)*2 + nj] = __builtin_amdgcn_mfma_f32_16x16x32_f16( \
            aR[mi][ks], bsrc[nj][ks], acc[(mh)*4 + mi][(nh)*2 + nj], 0, 0, 0); \
  } while (0)

    f32x4 acc[8][4];
#pragma unroll
    for (int i = 0; i < 8; ++i)
#pragma unroll
        for (int j = 0; j < 4; ++j) acc[i][j] = (f32x4)0.0f;

    h16x8 aR[4][2], bLo[2][2], bHi[2][2];
    fl4   vA0[4], vA1[4];   // fp32 A staging groups (issue->write gap = 2 phases)

    // ---- prologue: t0 fully staged (A regs + B gload), t1.B gload, t1.A in regs ----
    LOAD_A(vA0, 0, 0); LOAD_A(vA1, 1, 0);
    STAGE_B(0, 0, 0);  STAGE_B(0, 1, 0);
    STAGE_B(1, 0, 1);  STAGE_B(1, 1, 1);
    WRITE_A(A_B0H0, vA0); WRITE_A(A_B0H1, vA1);      // auto-vmcnt waits vA*, drains B t0 too
    LOAD_A(vA0, 0, 1); LOAD_A(vA1, 1, 1);            // t1.A -> written in-loop P0/P1
    asm volatile("s_waitcnt vmcnt(8) lgkmcnt(0)" ::: "memory");  // t0.B landed (t1.B + t1.A outstanding)
    __builtin_amdgcn_s_barrier();
    __builtin_amdgcn_sched_barrier(0);

    for (int it = 0; it < NKT / 2; ++it) {
        const int tA = (2 * it + 2) & (NKT - 1);   // wraps harmlessly on last iter
        const int tB = (2 * it + 3) & (NKT - 1);

        // P0: compute buf0 q(mh0,nlo); ds_write t_odd.A.h0 (auto-vmcnt drains P6.B too)
        READ_A(0, 0); READ_B(0, 0, bLo);
        WRITE_A(A_B1H0, vA0);
        PH_MID(); MFMA_Q(0, 0, bLo); PH_END();
        // P1: q(mh0,nhi); ds_write t_odd.A.h1 (drains P7.B)
        READ_B(0, 1, bHi);
        WRITE_A(A_B1H1, vA1);
        PH_MID(); MFMA_Q(0, 1, bHi); PH_END();
        // P2: q(mh1,nhi); gload buf0.B<-tA (region free since P1); issue tA.A.h0
        READ_A(0, 1);
        STAGE_B(0, 0, tA);
        LOAD_A(vA0, 0, tA);
        PH_MID(); MFMA_Q(1, 1, bHi); PH_END();
        // P3: q(mh1,nlo); gload buf0.B.h1<-tA; issue tA.A.h1
        STAGE_B(0, 1, tA);
        LOAD_A(vA1, 1, tA);
        PH_MID(); MFMA_Q(1, 0, bLo); PH_END();
        // P4: compute buf1 q(mh0,nlo); ds_write tA.A.h0 (buf0.A free since P2; drains P2.B)
        READ_A(1, 0); READ_B(1, 0, bLo);
        WRITE_A(A_B0H0, vA0);
        PH_MID(); MFMA_Q(0, 0, bLo); PH_END();
        // P5: q(mh0,nhi); ds_write tA.A.h1 (drains P3.B)
        READ_B(1, 1, bHi);
        WRITE_A(A_B0H1, vA1);
        PH_MID(); MFMA_Q(0, 1, bHi); PH_END();
        // P6: q(mh1,nhi); gload buf1.B<-tB (free since P5); issue tB.A.h0
        READ_A(1, 1);
        STAGE_B(1, 0, tB);
        LOAD_A(vA0, 0, tB);
        PH_MID(); MFMA_Q(1, 1, bHi); PH_END();
        // P7: q(mh1,nlo); gload buf1.B.h1<-tB; issue tB.A.h1 (written next P0/P1)
        STAGE_B(1, 1, tB);
        LOAD_A(vA1, 1, tB);
        PH_MID(); MFMA_Q(1, 0, bLo); PH_END();
    }

    // ---- epilogue: out = round((is*ws[n]*acc + bias[n]) / os) ----
    const float is = p_is[0];
    const float inv_os = 1.0f / p_os[0];
    const int colBase = n0 + wni * 64;

    float alpha[4], beta[4];
#pragma unroll
    for (int nj = 0; nj < 4; ++nj) {
        const int col = colBase + nj * 16 + r16;
        alpha[nj] = is * wscale[col] * inv_os;
        beta[nj]  = (float)bias[col] * inv_os;
    }

    // C/D layout (verified m89/m91, dtype-independent): col = lane&15, row = quad*4 + reg
#pragma unroll
    for (int mi = 0; mi < 8; ++mi) {
        const int row0 = m0 + wmi * 128 + mi * 16 + quad * 4;
#pragma unroll
        for (int nj = 0; nj < 4; ++nj) {
            const int col = colBase + nj * 16 + r16;
#pragma unroll
            for (int reg = 0; reg < 4; ++reg) {
                const float v = acc[mi][nj][reg] * alpha[nj] + beta[nj];
                __builtin_nontemporal_store(__float2int_rn(v),
                                            out + (int64_t)(row0 + reg) * NDIM + col);
            }
        }
    }
}

extern "C" void kernel_launch(void* const* d_in, const int* in_sizes, int n_in,
                              void* d_out, int out_size, void* d_ws, size_t ws_size,
                              hipStream_t stream) {
    (void)in_sizes; (void)n_in; (void)out_size; (void)ws_size;
    const float* x      = (const float*)d_in[0];
    const int*   weight = (const int*)d_in[1];
    const int*   bias   = (const int*)d_in[2];
    const float* wscale = (const float*)d_in[3];
    const float* p_is   = (const float*)d_in[4];
    const float* p_os   = (const float*)d_in[5];

    // workspace: wq fp16 [N,K] = 32 MiB (xq no longer exists)
    short* wq = (short*)d_ws;

    quant_w_kernel<<<2048, 256, 0, stream>>>(weight, wq);

    dim3 grid(NDIM / 256, MDIM / 256);   // 16 x 32 = 512 blocks
    gemm_fused_kernel<<<grid, 512, 0, stream>>>(x, wq, bias, wscale, p_is, p_os,
                                                (int*)d_out);
}

// Round 6
// 479.869 us; speedup vs baseline: 2.1577x; 1.3110x over previous
//
#include <hip/hip_runtime.h>
#include <stdint.h>

// Problem shape (fixed by the reference): M = B*S = 8192, K = DIN = 4096, N = DOUT = 4096
#define MDIM 8192
#define KDIM 4096
#define NDIM 4096
#define BK   64
#define NKT  (KDIM / BK)   // 64 K-tiles

typedef float f32x4 __attribute__((ext_vector_type(4)));
typedef _Float16 h16x8 __attribute__((ext_vector_type(8)));
typedef float fl4 __attribute__((ext_vector_type(4)));
typedef int i32x4 __attribute__((ext_vector_type(4)));

// async global->LDS, 16B per lane; LDS dest is wave-uniform base + lane*16 (HW semantics)
__device__ __forceinline__ void gload_lds16(const void* g, void* l) {
    __builtin_amdgcn_global_load_lds(
        (__attribute__((address_space(1))) void*)(uintptr_t)g,
        (__attribute__((address_space(3))) void*)(uintptr_t)l,
        16, 0, 0);
}

// ---------------- fused quant: one dispatch, both tensors (verified R2 form, fp16 out) ----
// blocks [0,2048): x fp32 -> xq fp16 (rint(x/is); integer-valued |v|<~350: fp16-exact)
// blocks [2048,3072): w int32 -> wq fp16 (|w|<=127: exact)
__global__ void __launch_bounds__(256) quant_kernel(const float* __restrict__ x,
                                                    short* __restrict__ xq,
                                                    const int* __restrict__ w,
                                                    short* __restrict__ wq,
                                                    const float* __restrict__ p_is) {
    if (blockIdx.x < 2048) {
        const float inv_is = 1.0f / p_is[0];
        const int64_t stride = (int64_t)2048 * 256 * 8;
        for (int64_t i = ((int64_t)blockIdx.x * 256 + threadIdx.x) * 8;
             i < (int64_t)MDIM * KDIM; i += stride) {
            fl4 a = __builtin_nontemporal_load((const fl4*)(x + i));
            fl4 b = __builtin_nontemporal_load((const fl4*)(x + i + 4));
            h16x8 o;
            o[0] = (_Float16)rintf(a[0] * inv_is);
            o[1] = (_Float16)rintf(a[1] * inv_is);
            o[2] = (_Float16)rintf(a[2] * inv_is);
            o[3] = (_Float16)rintf(a[3] * inv_is);
            o[4] = (_Float16)rintf(b[0] * inv_is);
            o[5] = (_Float16)rintf(b[1] * inv_is);
            o[6] = (_Float16)rintf(b[2] * inv_is);
            o[7] = (_Float16)rintf(b[3] * inv_is);
            *(h16x8*)(xq + i) = o;   // normal store: gemm re-reads xq, let L3 keep it
        }
    } else {
        const int64_t stride = (int64_t)1024 * 256 * 8;
        for (int64_t i = (((int64_t)blockIdx.x - 2048) * 256 + threadIdx.x) * 8;
             i < (int64_t)NDIM * KDIM; i += stride) {
            i32x4 a = *(const i32x4*)(w + i);
            i32x4 b = *(const i32x4*)(w + i + 4);
            h16x8 o;
            o[0] = (_Float16)(float)a[0];
            o[1] = (_Float16)(float)a[1];
            o[2] = (_Float16)(float)a[2];
            o[3] = (_Float16)(float)a[3];
            o[4] = (_Float16)(float)b[0];
            o[5] = (_Float16)(float)b[1];
            o[6] = (_Float16)(float)b[2];
            o[7] = (_Float16)(float)b[3];
            *(h16x8*)(wq + i) = o;
        }
    }
}

// ---------------- GEMM: 256x256 tile, BK=64, 8 waves, 8-phase, DEEP prefetch ----------------
// R9 = verified R2 gemm (f16, 246us, MfmaUtil 49) with ONLY the stage schedule changed:
// stages shifted 1 phase earlier -> 3-phase issue->consume margin, 3 half-tiles in flight,
// vmcnt(6) at P3/P7 (m201's exact T4 discipline: N = 2 loads x 3 half-tiles).
//
// Stage map (each STAGE_* = 2 gload_lds; region free = 1 phase after last ds_read):
//   P0: buf1.A.h1<-t1   [free since prev-P7; read prev-P6]
//   P2: buf0.B.h0<-tA   [free since P2; bLo/bHi reg-cached after P1]
//   P3: buf0.B.h1<-tA, buf0.A.h0<-tA   [A.h0 read P0 -> free P1+]
//   P4: buf0.A.h1<-tA   [read P2 -> free P3+]
//   P6: buf1.B.h0<-tB   [read P5 -> free P6]
//   P7: buf1.B.h1<-tB, buf1.A.h0<-tB   [A.h0 read P4]
// Queue proof (steady state): P3-end has 14 outstanding; oldest 8 = buf1(t1) complete
//   {prev-P6(2), prev-P7(4), P0(2)} -> vmcnt(6) exact. P7-end has 14; oldest 8 = buf0(tA)
//   {P2(2), P3(4), P4(2)} -> vmcnt(6) exact. Margins: every half-tile waited >=3 phases
//   after issue (was 2). Never vmcnt(0) in loop.

#define PH_MID() do { \
    __builtin_amdgcn_s_barrier(); \
    asm volatile("s_waitcnt lgkmcnt(0)" ::: "memory"); \
    __builtin_amdgcn_sched_barrier(0); \
    __builtin_amdgcn_s_setprio(1); \
  } while (0)

#define PH_END() do { \
    __builtin_amdgcn_s_setprio(0); \
    __builtin_amdgcn_s_barrier(); \
    __builtin_amdgcn_sched_barrier(0); \
  } while (0)

#define PH_END_VM6() do { \
    __builtin_amdgcn_s_setprio(0); \
    asm volatile("s_waitcnt vmcnt(6)" ::: "memory"); \
    __builtin_amdgcn_s_barrier(); \
    __builtin_amdgcn_sched_barrier(0); \
  } while (0)

__global__ void __launch_bounds__(512, 2) gemm_f16_kernel(
    const short* __restrict__ A,     // [MDIM][KDIM] fp16 bits (xq)
    const short* __restrict__ Bw,    // [NDIM][KDIM] fp16 bits (wq)
    const int* __restrict__ bias,    // [NDIM]
    const float* __restrict__ wscale,// [NDIM]
    const float* __restrict__ p_is,
    const float* __restrict__ p_os,
    int* __restrict__ out) {         // [MDIM][NDIM] int32
    // A bufs: lds[b*16384 + row*64 + ch*8]; B bufs: +32768. 65536 shorts = 128 KiB.
    __shared__ __align__(16) short lds[65536];

    const int tid  = threadIdx.x;
    const int lane = tid & 63;
    const int wave = tid >> 6;
    const int quad = lane >> 4;
    const int r16  = lane & 15;
    const int sw   = r16 & 7;

    // T1: bijective XCD swizzle over the 32x16 grid (neutral in R2 measurement; zero cost)
    const int flat  = blockIdx.y * gridDim.x + blockIdx.x;
    const int wgid  = (flat & 7) * 64 + (flat >> 3);
    const int m_blk = wgid >> 4;       // 0..31
    const int n_blk = wgid & 15;       // 0..15
    const int m0 = m_blk * 256;
    const int n0 = n_blk * 256;

    const int wmi = wave >> 2;         // 0..1  M wave-row (128 rows each)
    const int wni = wave & 3;          // 0..3  N wave-col (64 cols each)

    // ---- staging (write side): chunk c = l*512 + tid; row=c>>3, kc=c&7;
    //      source column chunk = kc ^ (row&7)  (rows +64 keep row&7 -> per-thread const)
    const int srow = tid >> 3;                       // 0..63
    const int skc  = (tid & 7) ^ (srow & 7);
    const short* gA = A  + (int64_t)(m0 + srow) * KDIM + skc * 8;
    const short* gB = Bw + (int64_t)(n0 + srow) * KDIM + skc * 8;

#define STAGE_A(b, ha, T) do { \
    const short* _g = gA + (int64_t)((ha) * 128) * KDIM + (T) * BK; \
    gload_lds16(_g,             &lds[(b)*16384 + (ha)*8192 + wave*512]); \
    gload_lds16(_g + 64*KDIM,   &lds[(b)*16384 + (ha)*8192 + 4096 + wave*512]); \
  } while (0)
#define STAGE_B(b, ha, T) do { \
    const short* _g = gB + (int64_t)((ha) * 128) * KDIM + (T) * BK; \
    gload_lds16(_g,             &lds[32768 + (b)*16384 + (ha)*8192 + wave*512]); \
    gload_lds16(_g + 64*KDIM,   &lds[32768 + (b)*16384 + (ha)*8192 + 4096 + wave*512]); \
  } while (0)

    // ---- read side: row = <mult of 8> + r16, so row&7 == sw; chunk = (ks*4|quad)^sw
    const int aRowOff = (wmi * 128 + r16) * 64;          // + (mh*64 + mi*16)*64
    const int bRowOff = 32768 + (wni * 64 + r16) * 64;   // + (nh*32 + nj*16)*64
    const int cOff0   = (quad ^ sw) * 8;
    const int cOff1   = cOff0 ^ 32;                      // ks=1 flips chunk bit 2

#define LDA(b, mh, mi, ks) \
    (*(const h16x8*)&lds[(b)*16384 + aRowOff + ((mh)*64 + (mi)*16)*64 + ((ks) ? cOff1 : cOff0)])
#define LDB(b, nh, nj, ks) \
    (*(const h16x8*)&lds[(b)*16384 + bRowOff + ((nh)*32 + (nj)*16)*64 + ((ks) ? cOff1 : cOff0)])

#define READ_A(b, mh) do { \
    _Pragma("unroll") for (int mi = 0; mi < 4; ++mi) { \
        aR[mi][0] = LDA(b, mh, mi, 0); aR[mi][1] = LDA(b, mh, mi, 1); } \
  } while (0)
#define READ_B(b, nh, dst) do { \
    _Pragma("unroll") for (int nj = 0; nj < 2; ++nj) { \
        dst[nj][0] = LDB(b, nh, nj, 0); dst[nj][1] = LDB(b, nh, nj, 1); } \
  } while (0)
#define MFMA_Q(mh, nh, bsrc) do { \
    _Pragma("unroll") for (int mi = 0; mi < 4; ++mi) \
    _Pragma("unroll") for (int nj = 0; nj < 2; ++nj) \
    _Pragma("unroll") for (int ks = 0; ks < 2; ++ks) \
        acc[(mh)*4 + mi][(nh)*2 + nj] = __builtin_amdgcn_mfma_f32_16x16x32_f16( \
            aR[mi][ks], bsrc[nj][ks], acc[(mh)*4 + mi][(nh)*2 + nj], 0, 0, 0); \
  } while (0)

    f32x4 acc[8][4];
#pragma unroll
    for (int i = 0; i < 8; ++i)
#pragma unroll
        for (int j = 0; j < 4; ++j) acc[i][j] = (f32x4)0.0f;

    h16x8 aR[4][2], bLo[2][2], bHi[2][2];

    // ---- prologue: t0 fully (8 ops) + t1 {B.h0, B.h1, A.h0} (6 ops); A.h1 of t1 at P0 ----
    STAGE_B(0, 0, 0);  STAGE_B(0, 1, 0);
    STAGE_A(0, 0, 0);  STAGE_A(0, 1, 0);
    STAGE_B(1, 0, 1);  STAGE_B(1, 1, 1);
    STAGE_A(1, 0, 1);
    asm volatile("s_waitcnt vmcnt(6)" ::: "memory");   // t0's 8 (oldest) landed
    __builtin_amdgcn_s_barrier();
    __builtin_amdgcn_sched_barrier(0);

    for (int it = 0; it < NKT / 2; ++it) {
        const int t1 = 2 * it + 1;
        const int tA = (2 * it + 2) & (NKT - 1);   // wraps harmlessly on last iter
        const int tB = (2 * it + 3) & (NKT - 1);

        // P0: compute buf0 q(mh0,nlo); stage buf1.A.h1<-t1 (read prev-P6, free)
        READ_A(0, 0); READ_B(0, 0, bLo);
        STAGE_A(1, 1, t1);
        asm volatile("s_waitcnt lgkmcnt(8)" ::: "memory");  // 12 ds_reads this phase
        PH_MID(); MFMA_Q(0, 0, bLo); PH_END();
        // P1: q(mh0,nhi); no stage
        READ_B(0, 1, bHi);
        PH_MID(); MFMA_Q(0, 1, bHi); PH_END();
        // P2: q(mh1,nhi); stage buf0.B.h0<-tA (B regs cached since P1)
        READ_A(0, 1);
        STAGE_B(0, 0, tA);
        PH_MID(); MFMA_Q(1, 1, bHi); PH_END();
        // P3: q(mh1,nlo); stage buf0.B.h1 + buf0.A.h0 <- tA; vmcnt(6): buf1(t1) landed
        STAGE_B(0, 1, tA);
        STAGE_A(0, 0, tA);
        PH_MID(); MFMA_Q(1, 0, bLo); PH_END_VM6();
        // P4: compute buf1 q(mh0,nlo); stage buf0.A.h1<-tA (read P2, free)
        READ_A(1, 0); READ_B(1, 0, bLo);
        STAGE_A(0, 1, tA);
        asm volatile("s_waitcnt lgkmcnt(8)" ::: "memory");
        PH_MID(); MFMA_Q(0, 0, bLo); PH_END();
        // P5: q(mh0,nhi); no stage
        READ_B(1, 1, bHi);
        PH_MID(); MFMA_Q(0, 1, bHi); PH_END();
        // P6: q(mh1,nhi); stage buf1.B.h0<-tB
        READ_A(1, 1);
        STAGE_B(1, 0, tB);
        PH_MID(); MFMA_Q(1, 1, bHi); PH_END();
        // P7: q(mh1,nlo); stage buf1.B.h1 + buf1.A.h0 <- tB; vmcnt(6): buf0(tA) landed
        STAGE_B(1, 1, tB);
        STAGE_A(1, 0, tB);
        PH_MID(); MFMA_Q(1, 0, bLo); PH_END_VM6();
    }

    // ---- epilogue: out = round((is*ws[n]*acc + bias[n]) / os) ----
    const float is = p_is[0];
    const float inv_os = 1.0f / p_os[0];
    const int colBase = n0 + wni * 64;

    float alpha[4], beta[4];
#pragma unroll
    for (int nj = 0; nj < 4; ++nj) {
        const int col = colBase + nj * 16 + r16;
        alpha[nj] = is * wscale[col] * inv_os;
        beta[nj]  = (float)bias[col] * inv_os;
    }

    // C/D layout (verified m89/m91, dtype-independent): col = lane&15, row = quad*4 + reg
#pragma unroll
    for (int mi = 0; mi < 8; ++mi) {
        const int row0 = m0 + wmi * 128 + mi * 16 + quad * 4;
#pragma unroll
        for (int nj = 0; nj < 4; ++nj) {
            const int col = colBase + nj * 16 + r16;
#pragma unroll
            for (int reg = 0; reg < 4; ++reg) {
                const float v = acc[mi][nj][reg] * alpha[nj] + beta[nj];
                __builtin_nontemporal_store(__float2int_rn(v),
                                            out + (int64_t)(row0 + reg) * NDIM + col);
            }
        }
    }
}

extern "C" void kernel_launch(void* const* d_in, const int* in_sizes, int n_in,
                              void* d_out, int out_size, void* d_ws, size_t ws_size,
                              hipStream_t stream) {
    (void)in_sizes; (void)n_in; (void)out_size; (void)ws_size;
    const float* x      = (const float*)d_in[0];
    const int*   weight = (const int*)d_in[1];
    const int*   bias   = (const int*)d_in[2];
    const float* wscale = (const float*)d_in[3];
    const float* p_is   = (const float*)d_in[4];
    const float* p_os   = (const float*)d_in[5];

    // workspace: xq fp16 [M,K] (64 MiB) + wq fp16 [N,K] (32 MiB) = 96 MiB
    short* xq = (short*)d_ws;
    short* wq = xq + (size_t)MDIM * KDIM;

    quant_kernel<<<3072, 256, 0, stream>>>(x, xq, weight, wq, p_is);

    dim3 grid(NDIM / 256, MDIM / 256);   // 16 x 32 = 512 blocks
    gemm_f16_kernel<<<grid, 512, 0, stream>>>(xq, wq, bias, wscale, p_is, p_os, (int*)d_out);
}